// Round 3
// baseline (3187.824 us; speedup 1.0000x reference)
//
#include <hip/hip_runtime.h>
#include <hip/hip_bf16.h>
#include <stdint.h>

// GRU-D encoder, MI355X persistent-kernel implementation, round 3.
// B=256, S=200, D=64, H=512, TD=8.
// Per 16-row block (rb): 4 z-WGs, 4 r-WGs (with in-WG split-K second GEMM),
// 2 sh-producer WGs, 1 gamma-producer WG, 4 epilogue WGs.  Fuel-bounded
// spins convert any would-be deadlock into a fast visible failure.

typedef unsigned short u16;
typedef unsigned int   u32;
typedef unsigned long long u64;
typedef short bfrag  __attribute__((ext_vector_type(8)));
typedef u16   u16x8  __attribute__((ext_vector_type(8)));
typedef float f32x4  __attribute__((ext_vector_type(4)));

#define NB 256
#define NS 200
#define ND 64
#define NH 512

#define MFMA(a,b,c) __builtin_amdgcn_mfma_f32_16x16x32_bf16((a),(b),(c),0,0,0)

union UQ  { u16x8 h; bfrag s; u64 u[2]; uint4 q; };
union UF2 { float f[2]; u64 u; };

__device__ __forceinline__ float b2f(u16 v){ union { float f; u32 u; } c; c.u = ((u32)v) << 16; return c.f; }
__device__ __forceinline__ u16 f2b(float f){ union { float f; u32 u; } c; c.f = f; u32 r = c.u + 0x7FFFu + ((c.u >> 16) & 1u); return (u16)(r >> 16); }
__device__ __forceinline__ float sigm(float x){ return 1.f / (1.f + __expf(-x)); }
__device__ __forceinline__ float tanh_f(float x){ return 1.f - 2.f / (1.f + __expf(2.f * x)); }

// agent-scope (coherence-point) 8B ops: cross-XCD visible without L2 inv/wb fences
__device__ __forceinline__ u64 cload64(const void* p){
  return __hip_atomic_load((const u64*)p, __ATOMIC_RELAXED, __HIP_MEMORY_SCOPE_AGENT);
}
__device__ __forceinline__ void cstore64(void* p, u64 v){
  __hip_atomic_store((u64*)p, v, __ATOMIC_RELAXED, __HIP_MEMORY_SCOPE_AGENT);
}
__device__ __forceinline__ void load8f_c(const float* p, float* f){
  UF2 w;
  w.u = cload64(p + 0); f[0]=w.f[0]; f[1]=w.f[1];
  w.u = cload64(p + 2); f[2]=w.f[0]; f[3]=w.f[1];
  w.u = cload64(p + 4); f[4]=w.f[0]; f[5]=w.f[1];
  w.u = cload64(p + 6); f[6]=w.f[0]; f[7]=w.f[1];
}
__device__ __forceinline__ void store8f_c(float* p, const float* f){
  UF2 w;
  w.f[0]=f[0]; w.f[1]=f[1]; cstore64(p + 0, w.u);
  w.f[0]=f[2]; w.f[1]=f[3]; cstore64(p + 2, w.u);
  w.f[0]=f[4]; w.f[1]=f[5]; cstore64(p + 4, w.u);
  w.f[0]=f[6]; w.f[1]=f[7]; cstore64(p + 6, w.u);
}
// fuel-bounded spin: returns false if the target never arrives (~30ms) so the
// kernel FAILS FAST instead of hanging the GPU/container.
__device__ __forceinline__ bool spin_ge(u32* f, u32 tgt){
  int fuel = 1 << 19;
  while (__hip_atomic_load(f, __ATOMIC_RELAXED, __HIP_MEMORY_SCOPE_AGENT) < tgt) {
    __builtin_amdgcn_s_sleep(1);
    if (--fuel == 0) return false;
  }
  return true;
}
// load 8 consecutive f32 of a weight row, round to bf16 MFMA fragment
__device__ __forceinline__ bfrag ldfrag(const float* src){
  f32x4 lo = *(const f32x4*)src;
  f32x4 hi = *(const f32x4*)(src + 4);
  UQ z;
  z.h[0]=f2b(lo[0]); z.h[1]=f2b(lo[1]); z.h[2]=f2b(lo[2]); z.h[3]=f2b(lo[3]);
  z.h[4]=f2b(hi[0]); z.h[5]=f2b(hi[1]); z.h[6]=f2b(hi[2]); z.h[7]=f2b(hi[3]);
  return z.s;
}

// ---------------- setup kernels ----------------

__global__ void transpose_k(const float* __restrict__ Wout, float* __restrict__ WT){
  int i = blockIdx.x * 256 + threadIdx.x;
  if (i < 520 * 512) { int k = i >> 9, ho = i & 511; WT[i] = Wout[ho * 520 + k]; }
}

__global__ void mean1_k(const float* __restrict__ x, const float* __restrict__ mask,
                        float* __restrict__ PX, float* __restrict__ PM){
  int s = blockIdx.x, tid = threadIdx.x;
  __shared__ float lx[256], lm[256];
  float xa = 0.f, ma = 0.f;
  for (int i = tid; i < NB * ND; i += 256) {
    int b = i >> 6, d = i & 63;
    size_t ix = ((size_t)b * NS + s) * 64 + d;
    float m = mask[ix];
    xa += m * x[ix]; ma += m;
  }
  lx[tid] = xa; lm[tid] = ma;
  __syncthreads();
  if (tid < 64) {
    PX[(size_t)s * 64 + tid] = lx[tid] + lx[tid + 64] + lx[tid + 128] + lx[tid + 192];
    PM[(size_t)s * 64 + tid] = lm[tid] + lm[tid + 64] + lm[tid + 128] + lm[tid + 192];
  }
}

__global__ void mean2_k(const float* __restrict__ PX, const float* __restrict__ PM,
                        float* __restrict__ XMEAN){
  int d = threadIdx.x;
  float sx = 0.f, sm = 0.f;
  for (int s = 0; s < NS; ++s){ sx += PX[s * 64 + d]; sm += PM[s * 64 + d]; }
  XMEAN[d] = sx / fmaxf(sm, 1.f);
}

// per-(b,d) time chains: delta scan, x_last scan, x_hat; writes [s][b][d] bf16 streams
__global__ void prep_k(const float* __restrict__ x, const float* __restrict__ mask,
                       const float* __restrict__ tc, const float* __restrict__ wdgx,
                       const float* __restrict__ bdgx, const float* __restrict__ XMEAN,
                       u16* __restrict__ XHAT, u16* __restrict__ MASKB, u16* __restrict__ DELTA){
  int g = blockIdx.x * 256 + threadIdx.x;
  int b = g >> 6, d = g & 63;
  float xmean = XMEAN[d], wx = wdgx[d], bx = bdgx[d];
  float xl = 0.f, del = 0.f, tprev = 0.f, mprev = 1.f;
  for (int s = 0; s < NS; ++s){
    float tv = tc[b * NS + s];
    float dtv = (s == 0) ? 0.f : (tv - tprev);
    tprev = tv;
    del = dtv + (1.f - mprev) * del;
    size_t ix = ((size_t)b * NS + s) * 64 + d;
    float m = mask[ix], xv = x[ix];
    float gx = __expf(-fmaxf(0.f, wx * del + bx));
    float xh = m * xv + (1.f - m) * (gx * xl + (1.f - gx) * xmean);
    size_t ox = ((size_t)s * NB + b) * 64 + d;
    XHAT[ox] = f2b(xh); MASKB[ox] = f2b(m); DELTA[ox] = f2b(del);
    xl = m * xv + (1.f - m) * xl;
    mprev = m;
  }
}

// ---------------- persistent recurrent kernel ----------------
// grid = 240 WGs, 256 threads (4 waves). rb = bid/15, role = bid%15:
//  0-3: z-gate   (each WG: 128 z-cols, K=640)
//  4-7: r-gate + split-K partial of (r*h_dec)@Uh (K-slice 128, all 512 out-cols)
//  8-9: sh producer (x_hat@Wh + m@Vh + bh), double-buffered, paced
//  10 : gamma_h(t+1) producer, double-buffered, paced
// 11-14: epilogue (sum 4 partials + tanh + blend; h_dec bf16)
__global__ __launch_bounds__(256, 1) void grud_rnn(
    const float* __restrict__ Um, const float* __restrict__ Wm, const float* __restrict__ Vm,
    const float* __restrict__ bv, const float* __restrict__ Wdg, const float* __restrict__ bdg,
    const u16* __restrict__ XHAT, const u16* __restrict__ MASKB, const u16* __restrict__ DELTA,
    u16* __restrict__ HDEC, float* __restrict__ ZB, float* __restrict__ PART,
    float* __restrict__ SHXP, float* __restrict__ GAM, u16* __restrict__ HALL,
    u32* __restrict__ flags)
{
  const int tid = threadIdx.x, lane = tid & 63, wid = tid >> 6, bid = blockIdx.x;
  const int rb = bid / 15, role = bid % 15, m0 = rb * 16;
  const int l16 = lane & 15, krow = lane >> 4, r4 = lane >> 2, cb = (lane & 3) * 8;
  u32* dZR = flags + rb * 32;           // z+r done: 8 / step
  u32* dSH = flags + 512 + rb * 32;     // sh done: 2 / step
  u32* dG  = flags + 1024 + rb * 32;    // gamma done: 1 per produced gamma(g)
  u32* d2  = flags + 1536 + rb * 32;    // epilogue done: 4 / step

  __shared__ u16 panel[80 * 16 * 8];    // A-panels [kb][row16][8] bf16 (20 KB)
  __shared__ u16 rhbuf[16 * 136];       // r*h_dec exchange, padded stride
  __shared__ float xb[4][16 * 136];     // per-wave transpose scratch (stride 136)
  __shared__ int s_ab;                  // abort flag (deadlock -> fail fast)
  float* xw = xb[wid];
  const f32x4 Z4 = {0.f, 0.f, 0.f, 0.f};
  if (tid == 0) s_ab = 0;
  __syncthreads();

  if (role < 8) {
    // ================= z / r gate WGs =================
    const bool isr = role >= 4;
    const int g = role & 3;                 // K-slice group (for r) / col group
    const int rc = g * 128 + wid * 32;      // col base within gate [0,512)
    const int gb = (isr ? 512 : 0) + rc;    // global gate row base in W/U/V/b

    bfrag BU[16][2], BX[2][2], BM[2][2];
    #pragma unroll
    for (int kk = 0; kk < 16; ++kk)
      #pragma unroll
      for (int t2 = 0; t2 < 2; ++t2)
        BU[kk][t2] = ldfrag(Um + (size_t)(gb + t2 * 16 + l16) * 512 + kk * 32 + krow * 8);
    #pragma unroll
    for (int kx = 0; kx < 2; ++kx)
      #pragma unroll
      for (int t2 = 0; t2 < 2; ++t2) {
        BX[kx][t2] = ldfrag(Wm + (size_t)(gb + t2 * 16 + l16) * 64 + kx * 32 + krow * 8);
        BM[kx][t2] = ldfrag(Vm + (size_t)(gb + t2 * 16 + l16) * 64 + kx * 32 + krow * 8);
      }
    bfrag BH[4][8];   // Uh[out-col nt][k-slice g*128+...], resident (r only)
    if (isr) {
      #pragma unroll
      for (int kf = 0; kf < 4; ++kf)
        #pragma unroll
        for (int nt = 0; nt < 8; ++nt)
          BH[kf][nt] = ldfrag(Um + (size_t)(1024 + (wid * 8 + nt) * 16 + l16) * 512
                              + g * 128 + kf * 32 + krow * 8);
    }
    const float bias0 = bv[gb + l16], bias1 = bv[gb + 16 + l16];

    for (int t = 0; t < NS; ++t) {
      { // stage x_hat/mask panels (kb 64..79) — off critical path
        const int kbx = tid >> 4, row = tid & 15;
        const u16* sp = (kbx < 8 ? XHAT : MASKB) + ((size_t)t * NB + m0 + row) * 64 + (kbx & 7) * 8;
        *(uint4*)&panel[((64 + kbx) * 16 + row) * 8] = *(const uint4*)sp;
      }
      __syncthreads();
      f32x4 acc0 = {bias0, bias0, bias0, bias0};
      f32x4 acc1 = {bias1, bias1, bias1, bias1};
      #pragma unroll
      for (int kx = 0; kx < 2; ++kx) {   // x/m MFMAs pre-flag
        bfrag ax = *(const bfrag*)&panel[((64 + kx * 4 + krow) * 16 + l16) * 8];
        acc0 = MFMA(ax, BX[kx][0], acc0); acc1 = MFMA(ax, BX[kx][1], acc1);
        bfrag am = *(const bfrag*)&panel[((72 + kx * 4 + krow) * 16 + l16) * 8];
        acc0 = MFMA(am, BM[kx][0], acc0); acc1 = MFMA(am, BM[kx][1], acc1);
      }
      if (tid == 0) { if (!spin_ge(d2, 4u * (u32)t)) s_ab = 1; }   // h_dec(t) ready
      __syncthreads();
      if (s_ab) break;
      #pragma unroll
      for (int i = 0; i < 4; ++i) {      // stage h_dec bf16 [16][512] -> panel kb 0..63
        const int off = tid * 64 + i * 16;
        const int row = off >> 10, kb = (off & 1023) >> 4;
        const u16* sp = HDEC + (size_t)(m0 + row) * 512 + kb * 8;
        u64 a = cload64(sp), b = cload64(sp + 4);
        u16* dp = &panel[(kb * 16 + row) * 8];
        *(u64*)dp = a; *(u64*)(dp + 4) = b;
      }
      __syncthreads();
      #pragma unroll
      for (int kk = 0; kk < 16; ++kk) {
        bfrag a = *(const bfrag*)&panel[((kk * 4 + krow) * 16 + l16) * 8];
        acc0 = MFMA(a, BU[kk][0], acc0); acc1 = MFMA(a, BU[kk][1], acc1);
      }
      #pragma unroll
      for (int j = 0; j < 4; ++j) {      // C-frag -> row-major via wave-private LDS
        xw[(krow * 4 + j) * 136 + l16] = acc0[j];
        xw[(krow * 4 + j) * 136 + 16 + l16] = acc1[j];
      }
      float s8[8];
      #pragma unroll
      for (int q = 0; q < 8; ++q) s8[q] = xw[r4 * 136 + cb + q];
      if (!isr) {
        float zf[8];
        #pragma unroll
        for (int q = 0; q < 8; ++q) zf[q] = sigm(s8[q]);
        store8f_c(ZB + (size_t)(m0 + r4) * 512 + rc + cb, zf);
      } else {
        // rh = sigm(r) * h_dec (bf16), exchange across the 4 waves via LDS
        UQ hv; hv.h = *(const u16x8*)&panel[(((rc + cb) >> 3) * 16 + r4) * 8];
        UQ pv;
        #pragma unroll
        for (int q = 0; q < 8; ++q) pv.h[q] = f2b(sigm(s8[q]) * b2f(hv.h[q]));
        *(u16x8*)&rhbuf[r4 * 136 + wid * 32 + cb] = pv.h;
        __syncthreads();
        bfrag af[4];
        #pragma unroll
        for (int kf = 0; kf < 4; ++kf)
          af[kf] = *(const bfrag*)&rhbuf[l16 * 136 + kf * 32 + krow * 8];
        f32x4 sacc[8];
        #pragma unroll
        for (int nt = 0; nt < 8; ++nt) {
          f32x4 s = Z4;
          #pragma unroll
          for (int kf = 0; kf < 4; ++kf) s = MFMA(af[kf], BH[kf][nt], s);
          sacc[nt] = s;
        }
        #pragma unroll
        for (int nt = 0; nt < 8; ++nt)
          #pragma unroll
          for (int j = 0; j < 4; ++j)
            xw[(krow * 4 + j) * 136 + nt * 16 + l16] = sacc[nt][j];
        float* dst = PART + (size_t)(rb * 4 + g) * 8192 + (size_t)r4 * 512
                     + wid * 128 + (lane & 3) * 32;
        #pragma unroll
        for (int c = 0; c < 8; ++c) {
          f32x4 v = *(const f32x4*)&xw[r4 * 136 + (lane & 3) * 32 + c * 4];
          UF2 w0; w0.f[0] = v[0]; w0.f[1] = v[1]; cstore64(dst + c * 4, w0.u);
          UF2 w1; w1.f[0] = v[2]; w1.f[1] = v[3]; cstore64(dst + c * 4 + 2, w1.u);
        }
      }
      asm volatile("s_waitcnt vmcnt(0)" ::: "memory");
      __syncthreads();
      if (tid == 0) __hip_atomic_fetch_add(dZR, 1u, __ATOMIC_RELAXED, __HIP_MEMORY_SCOPE_AGENT);
    }
  } else if (role < 10) {
    // ================= sh producer (x-part of h-candidate) =================
    const int shwg = role - 8;
    const int hbase = (shwg * 4 + wid) * 64;
    bfrag BS[4][4];
    #pragma unroll
    for (int kx = 0; kx < 4; ++kx)
      #pragma unroll
      for (int ct = 0; ct < 4; ++ct)
        BS[kx][ct] = (kx < 2)
          ? ldfrag(Wm + (size_t)(1024 + hbase + ct * 16 + l16) * 64 + kx * 32 + krow * 8)
          : ldfrag(Vm + (size_t)(1024 + hbase + ct * 16 + l16) * 64 + (kx - 2) * 32 + krow * 8);
    float bb[4];
    #pragma unroll
    for (int ct = 0; ct < 4; ++ct) bb[ct] = bv[1024 + hbase + ct * 16 + l16];

    for (int t = 0; t < NS; ++t) {
      { const int kbx = tid >> 4, row = tid & 15;
        const u16* sp = (kbx < 8 ? XHAT : MASKB) + ((size_t)t * NB + m0 + row) * 64 + (kbx & 7) * 8;
        *(uint4*)&panel[(kbx * 16 + row) * 8] = *(const uint4*)sp; }
      __syncthreads();
      f32x4 acc[4];
      #pragma unroll
      for (int ct = 0; ct < 4; ++ct) acc[ct] = (f32x4){bb[ct], bb[ct], bb[ct], bb[ct]};
      #pragma unroll
      for (int kx = 0; kx < 4; ++kx) {
        const int pk = (kx < 2) ? (kx * 4 + krow) : (8 + (kx - 2) * 4 + krow);
        bfrag a = *(const bfrag*)&panel[(pk * 16 + l16) * 8];
        #pragma unroll
        for (int ct = 0; ct < 4; ++ct) acc[ct] = MFMA(a, BS[kx][ct], acc[ct]);
      }
      #pragma unroll
      for (int ct = 0; ct < 4; ++ct)
        #pragma unroll
        for (int j = 0; j < 4; ++j)
          xw[(krow * 4 + j) * 136 + ct * 16 + l16] = acc[ct][j];
      float out[16];
      #pragma unroll
      for (int c = 0; c < 4; ++c) {
        f32x4 v = *(const f32x4*)&xw[r4 * 136 + (lane & 3) * 16 + c * 4];
        out[c*4] = v[0]; out[c*4+1] = v[1]; out[c*4+2] = v[2]; out[c*4+3] = v[3];
      }
      if (tid == 0 && t >= 2) { if (!spin_ge(d2, 4u * (u32)(t - 1))) s_ab = 1; }
      __syncthreads();
      if (s_ab) break;
      float* dst = SHXP + ((size_t)(t & 1) * 16 + rb) * 8192 + (size_t)r4 * 512
                   + hbase + (lane & 3) * 16;
      #pragma unroll
      for (int c = 0; c < 8; ++c) {
        UF2 w; w.f[0] = out[c*2]; w.f[1] = out[c*2+1]; cstore64(dst + c * 2, w.u);
      }
      asm volatile("s_waitcnt vmcnt(0)" ::: "memory");
      __syncthreads();
      if (tid == 0) __hip_atomic_fetch_add(dSH, 1u, __ATOMIC_RELAXED, __HIP_MEMORY_SCOPE_AGENT);
    }
  } else if (role == 10) {
    // ================= gamma_h producer =================
    bfrag BG[2][8];
    #pragma unroll
    for (int kx = 0; kx < 2; ++kx)
      #pragma unroll
      for (int ct = 0; ct < 8; ++ct)
        BG[kx][ct] = ldfrag(Wdg + (size_t)(wid * 128 + ct * 16 + l16) * 64 + kx * 32 + krow * 8);
    float gbias[8];
    #pragma unroll
    for (int ct = 0; ct < 8; ++ct) gbias[ct] = bdg[wid * 128 + ct * 16 + l16];

    for (int g2 = 1; g2 < NS; ++g2) {
      if (tid < 128) {
        const int kbx = tid >> 4, row = tid & 15;
        const u16* sp = DELTA + ((size_t)g2 * NB + m0 + row) * 64 + kbx * 8;
        *(uint4*)&panel[(kbx * 16 + row) * 8] = *(const uint4*)sp;
      }
      __syncthreads();
      f32x4 acc[8];
      #pragma unroll
      for (int ct = 0; ct < 8; ++ct) acc[ct] = (f32x4){gbias[ct], gbias[ct], gbias[ct], gbias[ct]};
      #pragma unroll
      for (int kx = 0; kx < 2; ++kx) {
        bfrag a = *(const bfrag*)&panel[((kx * 4 + krow) * 16 + l16) * 8];
        #pragma unroll
        for (int ct = 0; ct < 8; ++ct) acc[ct] = MFMA(a, BG[kx][ct], acc[ct]);
      }
      #pragma unroll
      for (int ct = 0; ct < 8; ++ct)
        #pragma unroll
        for (int j = 0; j < 4; ++j)
          xw[(krow * 4 + j) * 136 + ct * 16 + l16] = acc[ct][j];
      float gm[32];
      #pragma unroll
      for (int c = 0; c < 8; ++c) {
        f32x4 v = *(const f32x4*)&xw[r4 * 136 + (lane & 3) * 32 + c * 4];
        gm[c*4]   = __expf(-fmaxf(0.f, v[0]));
        gm[c*4+1] = __expf(-fmaxf(0.f, v[1]));
        gm[c*4+2] = __expf(-fmaxf(0.f, v[2]));
        gm[c*4+3] = __expf(-fmaxf(0.f, v[3]));
      }
      if (tid == 0 && g2 >= 3) { if (!spin_ge(d2, 4u * (u32)(g2 - 2))) s_ab = 1; }
      __syncthreads();
      if (s_ab) break;
      float* dst = GAM + ((size_t)(g2 & 1) * 16 + rb) * 8192 + (size_t)r4 * 512 + wid * 128 + (lane & 3) * 32;
      #pragma unroll
      for (int c = 0; c < 16; ++c) {
        UF2 w; w.f[0] = gm[c*2]; w.f[1] = gm[c*2+1]; cstore64(dst + c * 2, w.u);
      }
      asm volatile("s_waitcnt vmcnt(0)" ::: "memory");
      __syncthreads();
      if (tid == 0) __hip_atomic_fetch_add(dG, 1u, __ATOMIC_RELAXED, __HIP_MEMORY_SCOPE_AGENT);
    }
  } else {
    // ================= epilogue =================
    const int ewg = role - 11;
    const int n0 = (ewg * 4 + wid) * 32;
    float hd[8] = {0.f,0.f,0.f,0.f,0.f,0.f,0.f,0.f};   // h_dec(t), f32 in registers
    const size_t rowoff = (size_t)r4 * 512 + n0 + cb;

    for (int t = 0; t < NS; ++t) {
      // cheap waits first; their loads fly during the critical dZR poll
      if (tid == 64) { if (!spin_ge(dSH, 2u * (u32)(t + 1))) s_ab = 1; }
      if (tid == 128 && t < NS - 1) { if (!spin_ge(dG, (u32)(t + 1))) s_ab = 1; }
      __syncthreads();
      if (s_ab) break;
      float shx[8], gm[8];
      load8f_c(SHXP + ((size_t)(t & 1) * 16 + rb) * 8192 + rowoff, shx);
      if (t < NS - 1)
        load8f_c(GAM + ((size_t)((t + 1) & 1) * 16 + rb) * 8192 + rowoff, gm);
      if (tid == 0) { if (!spin_ge(dZR, 8u * (u32)(t + 1))) s_ab = 1; }
      __syncthreads();
      if (s_ab) break;
      float p0[8], p1[8], p2[8], p3[8], zz[8];
      load8f_c(PART + (size_t)(rb * 4 + 0) * 8192 + rowoff, p0);
      load8f_c(PART + (size_t)(rb * 4 + 1) * 8192 + rowoff, p1);
      load8f_c(PART + (size_t)(rb * 4 + 2) * 8192 + rowoff, p2);
      load8f_c(PART + (size_t)(rb * 4 + 3) * 8192 + rowoff, p3);
      load8f_c(ZB + (size_t)(m0 + r4) * 512 + n0 + cb, zz);
      UQ hw;
      float hn[8];
      #pragma unroll
      for (int q = 0; q < 8; ++q) {
        float til = tanh_f(shx[q] + p0[q] + p1[q] + p2[q] + p3[q]);
        hn[q] = (1.f - zz[q]) * hd[q] + zz[q] * til;
        hw.h[q] = f2b(hn[q]);
      }
      if (t < NS - 1) {
        UQ hv;
        #pragma unroll
        for (int q = 0; q < 8; ++q) { hd[q] = gm[q] * hn[q]; hv.h[q] = f2b(hd[q]); }
        u16* dp = HDEC + (size_t)(m0 + r4) * 512 + n0 + cb;
        cstore64(dp, hv.u[0]); cstore64(dp + 4, hv.u[1]);
      }
      asm volatile("s_waitcnt vmcnt(0)" ::: "memory");
      __syncthreads();
      if (tid == 0) __hip_atomic_fetch_add(d2, 1u, __ATOMIC_RELAXED, __HIP_MEMORY_SCOPE_AGENT);
      // HALL store moved OFF the critical path (only read by attn_k later)
      u16* hp = HALL + ((size_t)t * NB + m0 + r4) * 512 + n0 + cb;
      cstore64(hp, hw.u[0]); cstore64(hp + 4, hw.u[1]);
    }
  }
}

// ---------------- post kernels ----------------

__global__ void attn_k(const u16* __restrict__ HALL, const float* __restrict__ av,
                       float* __restrict__ ATTN){
  const int b = blockIdx.x, tid = threadIdx.x, lane = tid & 63, wid = tid >> 6;
  __shared__ float avs[512], wgt[256], red[8];
  for (int i = tid; i < 512; i += 256) avs[i] = av[i];
  __syncthreads();
  float val = -3.0e38f;
  if (tid < NS) {
    const u16* hp = HALL + ((size_t)tid * NB + b) * 512;
    float acc = 0.f;
    for (int h = 0; h < 512; h += 8) {
      UQ w; w.q = *(const uint4*)(hp + h);
      #pragma unroll
      for (int j = 0; j < 8; ++j) acc += b2f(w.h[j]) * avs[h + j];
    }
    val = acc * 0.04419417382415922f;   // 1/sqrt(512)
  }
  float m = val;
  #pragma unroll
  for (int off = 32; off; off >>= 1) m = fmaxf(m, __shfl_xor(m, off, 64));
  if (lane == 0) red[wid] = m;
  __syncthreads();
  m = fmaxf(fmaxf(red[0], red[1]), fmaxf(red[2], red[3]));
  float e = (tid < NS) ? __expf(val - m) : 0.f;
  float sum = e;
  #pragma unroll
  for (int off = 32; off; off >>= 1) sum += __shfl_xor(sum, off, 64);
  if (lane == 0) red[4 + wid] = sum;
  __syncthreads();
  const float ssum = red[4] + red[5] + red[6] + red[7];
  wgt[tid] = e / ssum;
  __syncthreads();
  float a0 = 0.f, a1 = 0.f;
  const int h0 = tid * 2;
  for (int s = 0; s < NS; ++s) {
    float w = wgt[s];
    u32 pr = *(const u32*)(HALL + ((size_t)s * NB + b) * 512 + h0);
    a0 += w * b2f((u16)(pr & 0xFFFFu));
    a1 += w * b2f((u16)(pr >> 16));
  }
  ATTN[(size_t)b * 512 + h0] = a0;
  ATTN[(size_t)b * 512 + h0 + 1] = a1;
}

// 4 batch rows per WG: WT re-read traffic 256MB -> 64MB
__global__ void out_k(const float* __restrict__ ATTN, const float* __restrict__ Ain,
                      const float* __restrict__ WT, const float* __restrict__ bout,
                      float* __restrict__ OUT){
  const int g = blockIdx.x, tid = threadIdx.x;
  __shared__ float ah[4][520];
  for (int i = tid; i < 4 * 520; i += 256) {
    int bb = i / 520, k = i % 520;
    int b = g * 4 + bb;
    ah[bb][k] = (k < 512) ? ATTN[(size_t)b * 512 + k] : Ain[b * 8 + (k - 512)];
  }
  __syncthreads();
  #pragma unroll
  for (int part = 0; part < 2; ++part) {
    const int ho = part * 256 + tid;
    float a0 = bout[ho], a1 = a0, a2 = a0, a3 = a0;
    for (int k = 0; k < 520; ++k) {
      float w = WT[(size_t)k * 512 + ho];
      a0 += ah[0][k] * w; a1 += ah[1][k] * w; a2 += ah[2][k] * w; a3 += ah[3][k] * w;
    }
    OUT[(size_t)(g * 4 + 0) * 512 + ho] = a0;
    OUT[(size_t)(g * 4 + 1) * 512 + ho] = a1;
    OUT[(size_t)(g * 4 + 2) * 512 + ho] = a2;
    OUT[(size_t)(g * 4 + 3) * 512 + ho] = a3;
  }
}

// ---------------- host ----------------

extern "C" void kernel_launch(void* const* d_in, const int* in_sizes, int n_in,
                              void* d_out, int out_size, void* d_ws, size_t ws_size,
                              hipStream_t stream) {
  (void)in_sizes; (void)n_in; (void)out_size; (void)ws_size;
  const float* x    = (const float*)d_in[0];
  const float* a_in = (const float*)d_in[1];
  const float* tc   = (const float*)d_in[2];
  const float* mask = (const float*)d_in[3];
  const float* wdgx = (const float*)d_in[4];
  const float* bdgx = (const float*)d_in[5];
  const float* Wdgh = (const float*)d_in[6];
  const float* bdgh = (const float*)d_in[7];
  const float* Wm   = (const float*)d_in[8];
  const float* Um   = (const float*)d_in[9];
  const float* Vm   = (const float*)d_in[10];
  const float* bvv  = (const float*)d_in[11];
  const float* attv = (const float*)d_in[12];
  const float* Wout = (const float*)d_in[13];
  const float* bout = (const float*)d_in[14];

  char* ws = (char*)d_ws;
  size_t o = 0;
  auto al = [&](size_t sz) { size_t r = o; o += (sz + 255) & ~(size_t)255; return r; };
  u32*   flags = (u32*)  (ws + al(8192));
  float* XMEAN = (float*)(ws + al(256));
  float* PX    = (float*)(ws + al((size_t)NS * 64 * 4));
  float* PM    = (float*)(ws + al((size_t)NS * 64 * 4));
  u16*   XHAT  = (u16*)  (ws + al((size_t)NS * NB * 64 * 2));
  u16*   MASKB = (u16*)  (ws + al((size_t)NS * NB * 64 * 2));
  u16*   DELTA = (u16*)  (ws + al((size_t)NS * NB * 64 * 2));
  u16*   HDEC  = (u16*)  (ws + al((size_t)NB * NH * 2));
  float* ZB    = (float*)(ws + al((size_t)NB * NH * 4));
  float* PARTB = (float*)(ws + al((size_t)16 * 4 * 8192 * 4));
  float* SHXP  = (float*)(ws + al((size_t)2 * 16 * 8192 * 4));
  float* GAM   = (float*)(ws + al((size_t)2 * 16 * 8192 * 4));
  u16*   HALL  = (u16*)  (ws + al((size_t)NS * NB * NH * 2));
  float* ATTN  = (float*)(ws + al((size_t)NB * NH * 4));
  float* WT    = (float*)(ws + al((size_t)520 * 512 * 4));

  hipMemsetAsync(flags, 0, 8192, stream);
  hipMemsetAsync(HDEC, 0, (size_t)NB * NH * 2, stream);

  transpose_k<<<(520 * 512 + 255) / 256, 256, 0, stream>>>(Wout, WT);
  mean1_k<<<NS, 256, 0, stream>>>(x, mask, PX, PM);
  mean2_k<<<1, 64, 0, stream>>>(PX, PM, XMEAN);
  prep_k<<<NB * ND / 256, 256, 0, stream>>>(x, mask, tc, wdgx, bdgx, XMEAN, XHAT, MASKB, DELTA);
  grud_rnn<<<240, 256, 0, stream>>>(Um, Wm, Vm, bvv, Wdgh, bdgh, XHAT, MASKB, DELTA,
                                    HDEC, ZB, PARTB, SHXP, GAM, HALL, flags);
  attn_k<<<NB, 256, 0, stream>>>(HALL, attv, ATTN);
  out_k<<<64, 256, 0, stream>>>(ATTN, a_in, WT, bout, (float*)d_out);
}

// Round 4
// 1933.729 us; speedup vs baseline: 1.6485x; 1.6485x over previous
//
#include <hip/hip_runtime.h>
#include <hip/hip_bf16.h>
#include <stdint.h>

// GRU-D encoder, MI355X persistent-kernel implementation, round 4.
// B=256, S=200, D=64, H=512, TD=8.
// Per 16-row chain (rb): 4 symmetric gate-WGs (each owns a 128-col strip of
// z, r AND Uh with register-resident weights; two 4KB bf16 all-gathers per
// step), 2 paced x-part producer WGs, 1 paced gamma producer WG.
// 7 WGs/rb x 16 rb = 112 WGs. All spins fuel-bounded (fail fast, no hang).

typedef unsigned short u16;
typedef unsigned int   u32;
typedef unsigned long long u64;
typedef short bfrag  __attribute__((ext_vector_type(8)));
typedef u16   u16x8  __attribute__((ext_vector_type(8)));
typedef float f32x4  __attribute__((ext_vector_type(4)));

#define NB 256
#define NS 200
#define ND 64
#define NH 512

#define MFMA(a,b,c) __builtin_amdgcn_mfma_f32_16x16x32_bf16((a),(b),(c),0,0,0)

union UQ  { u16x8 h; bfrag s; u64 u[2]; uint4 q; };
union UF2 { float f[2]; u64 u; };

__device__ __forceinline__ float b2f(u16 v){ union { float f; u32 u; } c; c.u = ((u32)v) << 16; return c.f; }
__device__ __forceinline__ u16 f2b(float f){ union { float f; u32 u; } c; c.f = f; u32 r = c.u + 0x7FFFu + ((c.u >> 16) & 1u); return (u16)(r >> 16); }
__device__ __forceinline__ float sigm(float x){ return 1.f / (1.f + __expf(-x)); }
__device__ __forceinline__ float tanh_f(float x){ return 1.f - 2.f / (1.f + __expf(2.f * x)); }

// agent-scope (coherence-point) 8B ops: cross-XCD visible without L2 inv/wb fences
__device__ __forceinline__ u64 cload64(const void* p){
  return __hip_atomic_load((const u64*)p, __ATOMIC_RELAXED, __HIP_MEMORY_SCOPE_AGENT);
}
__device__ __forceinline__ void cstore64(void* p, u64 v){
  __hip_atomic_store((u64*)p, v, __ATOMIC_RELAXED, __HIP_MEMORY_SCOPE_AGENT);
}
// fuel-bounded spin: returns false if the target never arrives so the kernel
// fails fast instead of hanging the GPU/container.
__device__ __forceinline__ bool spin_ge(u32* f, u32 tgt){
  int fuel = 1 << 19;
  while (__hip_atomic_load(f, __ATOMIC_RELAXED, __HIP_MEMORY_SCOPE_AGENT) < tgt) {
    __builtin_amdgcn_s_sleep(1);
    if (--fuel == 0) return false;
  }
  return true;
}
__device__ __forceinline__ void flag_add(u32* f){
  __hip_atomic_fetch_add(f, 1u, __ATOMIC_RELAXED, __HIP_MEMORY_SCOPE_AGENT);
}
// load 8 consecutive f32 of a weight row, round to bf16 MFMA fragment
__device__ __forceinline__ bfrag ldfrag(const float* src){
  f32x4 lo = *(const f32x4*)src;
  f32x4 hi = *(const f32x4*)(src + 4);
  UQ z;
  z.h[0]=f2b(lo[0]); z.h[1]=f2b(lo[1]); z.h[2]=f2b(lo[2]); z.h[3]=f2b(lo[3]);
  z.h[4]=f2b(hi[0]); z.h[5]=f2b(hi[1]); z.h[6]=f2b(hi[2]); z.h[7]=f2b(hi[3]);
  return z.s;
}

// ---------------- setup kernels ----------------

__global__ void transpose_k(const float* __restrict__ Wout, float* __restrict__ WT){
  int i = blockIdx.x * 256 + threadIdx.x;
  if (i < 520 * 512) { int k = i >> 9, ho = i & 511; WT[i] = Wout[ho * 520 + k]; }
}

__global__ void mean1_k(const float* __restrict__ x, const float* __restrict__ mask,
                        float* __restrict__ PX, float* __restrict__ PM){
  int s = blockIdx.x, tid = threadIdx.x;
  __shared__ float lx[256], lm[256];
  float xa = 0.f, ma = 0.f;
  for (int i = tid; i < NB * ND; i += 256) {
    int b = i >> 6, d = i & 63;
    size_t ix = ((size_t)b * NS + s) * 64 + d;
    float m = mask[ix];
    xa += m * x[ix]; ma += m;
  }
  lx[tid] = xa; lm[tid] = ma;
  __syncthreads();
  if (tid < 64) {
    PX[(size_t)s * 64 + tid] = lx[tid] + lx[tid + 64] + lx[tid + 128] + lx[tid + 192];
    PM[(size_t)s * 64 + tid] = lm[tid] + lm[tid + 64] + lm[tid + 128] + lm[tid + 192];
  }
}

__global__ void mean2_k(const float* __restrict__ PX, const float* __restrict__ PM,
                        float* __restrict__ XMEAN){
  int d = threadIdx.x;
  float sx = 0.f, sm = 0.f;
  for (int s = 0; s < NS; ++s){ sx += PX[s * 64 + d]; sm += PM[s * 64 + d]; }
  XMEAN[d] = sx / fmaxf(sm, 1.f);
}

// per-(b,d) time chains: delta scan, x_last scan, x_hat; writes [s][b][d] bf16
__global__ void prep_k(const float* __restrict__ x, const float* __restrict__ mask,
                       const float* __restrict__ tc, const float* __restrict__ wdgx,
                       const float* __restrict__ bdgx, const float* __restrict__ XMEAN,
                       u16* __restrict__ XHAT, u16* __restrict__ MASKB, u16* __restrict__ DELTA){
  int g = blockIdx.x * 256 + threadIdx.x;
  int b = g >> 6, d = g & 63;
  float xmean = XMEAN[d], wx = wdgx[d], bx = bdgx[d];
  float xl = 0.f, del = 0.f, tprev = 0.f, mprev = 1.f;
  for (int s = 0; s < NS; ++s){
    float tv = tc[b * NS + s];
    float dtv = (s == 0) ? 0.f : (tv - tprev);
    tprev = tv;
    del = dtv + (1.f - mprev) * del;
    size_t ix = ((size_t)b * NS + s) * 64 + d;
    float m = mask[ix], xv = x[ix];
    float gx = __expf(-fmaxf(0.f, wx * del + bx));
    float xh = m * xv + (1.f - m) * (gx * xl + (1.f - gx) * xmean);
    size_t ox = ((size_t)s * NB + b) * 64 + d;
    XHAT[ox] = f2b(xh); MASKB[ox] = f2b(m); DELTA[ox] = f2b(del);
    xl = m * xv + (1.f - m) * xl;
    mprev = m;
  }
}

// ---------------- persistent recurrent kernel ----------------
// grid = 112 WGs (16 rb x 7), 256 threads (4 waves).
// role 0..3 : gate WG g — strip cols [g*128, g*128+128) of z, r, Uh.
// role 4..5 : x-part producer (cols p*768..+768 of [z|r|h] pre-activations)
// role 6    : gamma producer.
__global__ __launch_bounds__(256, 1) void grud_rnn(
    const float* __restrict__ Um, const float* __restrict__ Wm, const float* __restrict__ Vm,
    const float* __restrict__ bv, const float* __restrict__ Wdg, const float* __restrict__ bdg,
    const u16* __restrict__ XHAT, const u16* __restrict__ MASKB, const u16* __restrict__ DELTA,
    u16* __restrict__ HDECB, u16* __restrict__ RHB, u16* __restrict__ XPART,
    u16* __restrict__ GAMB, u16* __restrict__ HALL, u32* __restrict__ flags)
{
  const int tid = threadIdx.x, lane = tid & 63, wid = tid >> 6, bid = blockIdx.x;
  const int rb = bid / 7, role = bid % 7, m0 = rb * 16;
  const int l16 = lane & 15, krow = lane >> 4, r4 = lane >> 2, cb = (lane & 3) * 8;
  u32* FH = flags + rb * 128;        // h_dec(t+1) published: 4/step
  u32* FR = flags + rb * 128 + 32;   // rh(t) published: 4/step
  u32* FX = flags + rb * 128 + 64;   // xpart(t) ready: 2/step
  u32* FG = flags + rb * 128 + 96;   // gamma(tt) ready: 1 per tt=1..

  __shared__ u16 hpanel[64 * 16 * 8];   // h_dec A-panels [kb][row][8] (16 KB)
  __shared__ u16 rhpanel[64 * 16 * 8];  // rh A-panels (16 KB)
  __shared__ float xb[4][16 * 33];      // per-wave transpose scratch
  __shared__ int s_ab;
  float* xw = xb[wid];
  const f32x4 Z4 = {0.f, 0.f, 0.f, 0.f};
  if (tid == 0) s_ab = 0;
  __syncthreads();

  if (role < 4) {
    // ================= gate WG =================
    const int c0g = role * 128 + wid * 32;   // wave's absolute col strip base
    bfrag BUz[16][2], BUr[16][2], BUh[16][2];
    #pragma unroll
    for (int kk = 0; kk < 16; ++kk) {
      #pragma unroll
      for (int t2 = 0; t2 < 2; ++t2) {
        const size_t ko = (size_t)(kk * 32 + krow * 8);
        BUz[kk][t2] = ldfrag(Um + (size_t)(       c0g + t2 * 16 + l16) * 512 + ko);
        BUr[kk][t2] = ldfrag(Um + (size_t)(512  + c0g + t2 * 16 + l16) * 512 + ko);
        BUh[kk][t2] = ldfrag(Um + (size_t)(1024 + c0g + t2 * 16 + l16) * 512 + ko);
      }
    }

    for (int t = 0; t < NS; ++t) {
      const int slot = t & 1;
      // ---- polls (parallel, different threads) ----
      if (tid == 0 && t > 0)  { if (!spin_ge(FH, 4u * (u32)t)) s_ab = 1; }
      if (tid == 64)          { if (!spin_ge(FX, 2u * (u32)(t + 1))) s_ab = 1; }
      if (tid == 128)         { u32 gt = (t + 1 < NS) ? (u32)(t + 1) : (u32)(NS - 1);
                                if (!spin_ge(FG, gt)) s_ab = 1; }
      __syncthreads();
      if (s_ab) break;
      // ---- early per-lane loads: xpart strips + gamma(t+1) strip ----
      const u16* xpb = XPART + (((size_t)slot * 16 + rb) * 16 + r4) * 1536;
      u64 xz0 = cload64(xpb + c0g + cb),        xz1 = cload64(xpb + c0g + cb + 4);
      u64 xr0 = cload64(xpb + 512 + c0g + cb),  xr1 = cload64(xpb + 512 + c0g + cb + 4);
      u64 xh0 = cload64(xpb + 1024 + c0g + cb), xh1 = cload64(xpb + 1024 + c0g + cb + 4);
      u64 gm0 = 0, gm1 = 0;
      if (t + 1 < NS) {
        const u16* gpb = GAMB + (((size_t)((t + 1) & 1) * 16 + rb) * 16 + r4) * 512 + c0g + cb;
        gm0 = cload64(gpb); gm1 = cload64(gpb + 4);
      }
      // ---- stage h_dec(t) panel (pre-multiplied by gamma at publish) ----
      {
        const int srow = tid >> 4, sc = (tid & 15) * 32;
        u16* dp = &hpanel[((sc >> 3) * 16 + srow) * 8];
        if (t > 0) {
          const u16* hs = HDECB + (size_t)(m0 + srow) * 512 + sc;
          u64 a0 = cload64(hs),      a1 = cload64(hs + 4),  a2 = cload64(hs + 8),  a3 = cload64(hs + 12);
          u64 a4 = cload64(hs + 16), a5 = cload64(hs + 20), a6 = cload64(hs + 24), a7 = cload64(hs + 28);
          *(u64*)(dp)       = a0; *(u64*)(dp + 4)   = a1;
          *(u64*)(dp + 128) = a2; *(u64*)(dp + 132) = a3;
          *(u64*)(dp + 256) = a4; *(u64*)(dp + 260) = a5;
          *(u64*)(dp + 384) = a6; *(u64*)(dp + 388) = a7;
        } else {
          *(u64*)(dp)       = 0; *(u64*)(dp + 4)   = 0;
          *(u64*)(dp + 128) = 0; *(u64*)(dp + 132) = 0;
          *(u64*)(dp + 256) = 0; *(u64*)(dp + 260) = 0;
          *(u64*)(dp + 384) = 0; *(u64*)(dp + 388) = 0;
        }
      }
      __syncthreads();
      // ---- r GEMM (K=512) ----
      f32x4 ar0 = Z4, ar1 = Z4;
      #pragma unroll
      for (int kk = 0; kk < 16; ++kk) {
        bfrag a = *(const bfrag*)&hpanel[((kk * 4 + krow) * 16 + l16) * 8];
        ar0 = MFMA(a, BUr[kk][0], ar0); ar1 = MFMA(a, BUr[kk][1], ar1);
      }
      #pragma unroll
      for (int j = 0; j < 4; ++j) { xw[(krow*4+j)*33 + l16] = ar0[j]; xw[(krow*4+j)*33 + 16 + l16] = ar1[j]; }
      UQ xru; xru.u[0] = xr0; xru.u[1] = xr1;
      UQ hdu; hdu.h = *(const u16x8*)&hpanel[(((c0g + cb) >> 3) * 16 + r4) * 8];
      UQ rhv;
      #pragma unroll
      for (int q = 0; q < 8; ++q) {
        float rv = sigm(b2f(xru.h[q]) + xw[r4 * 33 + cb + q]);
        rhv.h[q] = f2b(rv * b2f(hdu.h[q]));
      }
      { u16* dst = RHB + (size_t)(m0 + r4) * 512 + c0g + cb;
        cstore64(dst, rhv.u[0]); cstore64(dst + 4, rhv.u[1]); }
      asm volatile("s_waitcnt vmcnt(0)" ::: "memory");
      __syncthreads();
      if (tid == 0) flag_add(FR);
      // ---- z GEMM (fills the rh round-trip latency) ----
      f32x4 az0 = Z4, az1 = Z4;
      #pragma unroll
      for (int kk = 0; kk < 16; ++kk) {
        bfrag a = *(const bfrag*)&hpanel[((kk * 4 + krow) * 16 + l16) * 8];
        az0 = MFMA(a, BUz[kk][0], az0); az1 = MFMA(a, BUz[kk][1], az1);
      }
      #pragma unroll
      for (int j = 0; j < 4; ++j) { xw[(krow*4+j)*33 + l16] = az0[j]; xw[(krow*4+j)*33 + 16 + l16] = az1[j]; }
      UQ xzu; xzu.u[0] = xz0; xzu.u[1] = xz1;
      float zz8[8];
      #pragma unroll
      for (int q = 0; q < 8; ++q) zz8[q] = sigm(b2f(xzu.h[q]) + xw[r4 * 33 + cb + q]);
      // ---- wait rh all-gather, stage rh panel ----
      if (tid == 0) { if (!spin_ge(FR, 4u * (u32)(t + 1))) s_ab = 1; }
      __syncthreads();
      if (s_ab) break;
      {
        const int srow = tid >> 4, sc = (tid & 15) * 32;
        const u16* rs = RHB + (size_t)(m0 + srow) * 512 + sc;
        u64 a0 = cload64(rs),      a1 = cload64(rs + 4),  a2 = cload64(rs + 8),  a3 = cload64(rs + 12);
        u64 a4 = cload64(rs + 16), a5 = cload64(rs + 20), a6 = cload64(rs + 24), a7 = cload64(rs + 28);
        u16* dp = &rhpanel[((sc >> 3) * 16 + srow) * 8];
        *(u64*)(dp)       = a0; *(u64*)(dp + 4)   = a1;
        *(u64*)(dp + 128) = a2; *(u64*)(dp + 132) = a3;
        *(u64*)(dp + 256) = a4; *(u64*)(dp + 260) = a5;
        *(u64*)(dp + 384) = a6; *(u64*)(dp + 388) = a7;
      }
      __syncthreads();
      // ---- Uh GEMM + blend ----
      f32x4 ah0 = Z4, ah1 = Z4;
      #pragma unroll
      for (int kk = 0; kk < 16; ++kk) {
        bfrag a = *(const bfrag*)&rhpanel[((kk * 4 + krow) * 16 + l16) * 8];
        ah0 = MFMA(a, BUh[kk][0], ah0); ah1 = MFMA(a, BUh[kk][1], ah1);
      }
      #pragma unroll
      for (int j = 0; j < 4; ++j) { xw[(krow*4+j)*33 + l16] = ah0[j]; xw[(krow*4+j)*33 + 16 + l16] = ah1[j]; }
      UQ xhu; xhu.u[0] = xh0; xhu.u[1] = xh1;
      UQ hwv; float hn8[8];
      #pragma unroll
      for (int q = 0; q < 8; ++q) {
        float til = tanh_f(b2f(xhu.h[q]) + xw[r4 * 33 + cb + q]);
        float hdq = b2f(hdu.h[q]);
        float hv = (1.f - zz8[q]) * hdq + zz8[q] * til;
        hn8[q] = hv; hwv.h[q] = f2b(hv);
      }
      if (t + 1 < NS) {   // publish h_dec(t+1) = gamma(t+1) * h_new
        UQ gmu; gmu.u[0] = gm0; gmu.u[1] = gm1;
        UQ hdn;
        #pragma unroll
        for (int q = 0; q < 8; ++q) hdn.h[q] = f2b(b2f(gmu.h[q]) * hn8[q]);
        u16* dp2 = HDECB + (size_t)(m0 + r4) * 512 + c0g + cb;
        cstore64(dp2, hdn.u[0]); cstore64(dp2 + 4, hdn.u[1]);
      }
      asm volatile("s_waitcnt vmcnt(0)" ::: "memory");
      __syncthreads();
      if (tid == 0) flag_add(FH);
      // HALL store off the critical path (read only by attn_k later)
      *(uint4*)(HALL + ((size_t)t * NB + m0 + r4) * 512 + c0g + cb) = hwv.q;
    }
  } else if (role < 6) {
    // ================= x-part producer =================
    const int p = role - 4;
    const int wbase = p * 768 + wid * 192;   // wave col base in [0,1536)
    bfrag BW[12][2], BV2[12][2];
    #pragma unroll
    for (int ct = 0; ct < 12; ++ct)
      #pragma unroll
      for (int kx = 0; kx < 2; ++kx) {
        BW[ct][kx]  = ldfrag(Wm + (size_t)(wbase + ct * 16 + l16) * 64 + kx * 32 + krow * 8);
        BV2[ct][kx] = ldfrag(Vm + (size_t)(wbase + ct * 16 + l16) * 64 + kx * 32 + krow * 8);
      }
    float bias6[6][8];
    #pragma unroll
    for (int grp = 0; grp < 6; ++grp)
      #pragma unroll
      for (int q = 0; q < 8; ++q) bias6[grp][q] = bv[wbase + grp * 32 + cb + q];

    for (int t = 0; t < NS; ++t) {
      if (tid == 0 && t >= 2) { if (!spin_ge(FH, 4u * (u32)(t - 1))) s_ab = 1; }
      { const int kb = tid >> 4, row = tid & 15;
        const u16* sp = (kb < 8 ? XHAT : MASKB) + ((size_t)t * NB + m0 + row) * 64 + (kb & 7) * 8;
        *(uint4*)&hpanel[(kb * 16 + row) * 8] = *(const uint4*)sp; }
      __syncthreads();
      if (s_ab) break;
      u16* orow_ = XPART + (((size_t)(t & 1) * 16 + rb) * 16 + r4) * 1536 + wbase;
      #pragma unroll
      for (int grp = 0; grp < 6; ++grp) {
        f32x4 ac0 = Z4, ac1 = Z4;
        #pragma unroll
        for (int kx = 0; kx < 2; ++kx) {
          bfrag ax = *(const bfrag*)&hpanel[((kx * 4 + krow) * 16 + l16) * 8];
          ac0 = MFMA(ax, BW[grp*2][kx], ac0); ac1 = MFMA(ax, BW[grp*2+1][kx], ac1);
          bfrag am = *(const bfrag*)&hpanel[((8 + kx * 4 + krow) * 16 + l16) * 8];
          ac0 = MFMA(am, BV2[grp*2][kx], ac0); ac1 = MFMA(am, BV2[grp*2+1][kx], ac1);
        }
        #pragma unroll
        for (int j = 0; j < 4; ++j) { xw[(krow*4+j)*33 + l16] = ac0[j]; xw[(krow*4+j)*33 + 16 + l16] = ac1[j]; }
        UQ ov;
        #pragma unroll
        for (int q = 0; q < 8; ++q) ov.h[q] = f2b(xw[r4 * 33 + cb + q] + bias6[grp][q]);
        cstore64(orow_ + grp * 32 + cb, ov.u[0]); cstore64(orow_ + grp * 32 + cb + 4, ov.u[1]);
      }
      asm volatile("s_waitcnt vmcnt(0)" ::: "memory");
      __syncthreads();
      if (tid == 0) flag_add(FX);
    }
  } else {
    // ================= gamma producer =================
    bfrag BG[8][2];
    #pragma unroll
    for (int ct = 0; ct < 8; ++ct)
      #pragma unroll
      for (int kx = 0; kx < 2; ++kx)
        BG[ct][kx] = ldfrag(Wdg + (size_t)(wid * 128 + ct * 16 + l16) * 64 + kx * 32 + krow * 8);
    float gb4[4][8];
    #pragma unroll
    for (int grp = 0; grp < 4; ++grp)
      #pragma unroll
      for (int q = 0; q < 8; ++q) gb4[grp][q] = bdg[wid * 128 + grp * 32 + cb + q];

    for (int tt = 1; tt < NS; ++tt) {
      if (tid == 0 && tt >= 3) { if (!spin_ge(FH, 4u * (u32)(tt - 2))) s_ab = 1; }
      if (tid < 128) {
        const int kb = tid >> 4, row = tid & 15;
        const u16* sp = DELTA + ((size_t)tt * NB + m0 + row) * 64 + kb * 8;
        *(uint4*)&hpanel[(kb * 16 + row) * 8] = *(const uint4*)sp;
      }
      __syncthreads();
      if (s_ab) break;
      u16* orow_ = GAMB + (((size_t)(tt & 1) * 16 + rb) * 16 + r4) * 512 + wid * 128;
      #pragma unroll
      for (int grp = 0; grp < 4; ++grp) {
        f32x4 ac0 = Z4, ac1 = Z4;
        #pragma unroll
        for (int kx = 0; kx < 2; ++kx) {
          bfrag a = *(const bfrag*)&hpanel[((kx * 4 + krow) * 16 + l16) * 8];
          ac0 = MFMA(a, BG[grp*2][kx], ac0); ac1 = MFMA(a, BG[grp*2+1][kx], ac1);
        }
        #pragma unroll
        for (int j = 0; j < 4; ++j) { xw[(krow*4+j)*33 + l16] = ac0[j]; xw[(krow*4+j)*33 + 16 + l16] = ac1[j]; }
        UQ ov;
        #pragma unroll
        for (int q = 0; q < 8; ++q)
          ov.h[q] = f2b(__expf(-fmaxf(0.f, xw[r4 * 33 + cb + q] + gb4[grp][q])));
        cstore64(orow_ + grp * 32 + cb, ov.u[0]); cstore64(orow_ + grp * 32 + cb + 4, ov.u[1]);
      }
      asm volatile("s_waitcnt vmcnt(0)" ::: "memory");
      __syncthreads();
      if (tid == 0) flag_add(FG);
    }
  }
}

// ---------------- post kernels ----------------

__global__ void attn_k(const u16* __restrict__ HALL, const float* __restrict__ av,
                       float* __restrict__ ATTN){
  const int b = blockIdx.x, tid = threadIdx.x, lane = tid & 63, wid = tid >> 6;
  __shared__ float avs[512], wgt[256], red[8];
  for (int i = tid; i < 512; i += 256) avs[i] = av[i];
  __syncthreads();
  float val = -3.0e38f;
  if (tid < NS) {
    const u16* hp = HALL + ((size_t)tid * NB + b) * 512;
    float acc = 0.f;
    for (int h = 0; h < 512; h += 8) {
      UQ w; w.q = *(const uint4*)(hp + h);
      #pragma unroll
      for (int j = 0; j < 8; ++j) acc += b2f(w.h[j]) * avs[h + j];
    }
    val = acc * 0.04419417382415922f;   // 1/sqrt(512)
  }
  float m = val;
  #pragma unroll
  for (int off = 32; off; off >>= 1) m = fmaxf(m, __shfl_xor(m, off, 64));
  if (lane == 0) red[wid] = m;
  __syncthreads();
  m = fmaxf(fmaxf(red[0], red[1]), fmaxf(red[2], red[3]));
  float e = (tid < NS) ? __expf(val - m) : 0.f;
  float sum = e;
  #pragma unroll
  for (int off = 32; off; off >>= 1) sum += __shfl_xor(sum, off, 64);
  if (lane == 0) red[4 + wid] = sum;
  __syncthreads();
  const float ssum = red[4] + red[5] + red[6] + red[7];
  wgt[tid] = e / ssum;
  __syncthreads();
  float a0 = 0.f, a1 = 0.f;
  const int h0 = tid * 2;
  for (int s = 0; s < NS; ++s) {
    float w = wgt[s];
    u32 pr = *(const u32*)(HALL + ((size_t)s * NB + b) * 512 + h0);
    a0 += w * b2f((u16)(pr & 0xFFFFu));
    a1 += w * b2f((u16)(pr >> 16));
  }
  ATTN[(size_t)b * 512 + h0] = a0;
  ATTN[(size_t)b * 512 + h0 + 1] = a1;
}

// 4 batch rows per WG: WT re-read traffic 256MB -> 64MB
__global__ void out_k(const float* __restrict__ ATTN, const float* __restrict__ Ain,
                      const float* __restrict__ WT, const float* __restrict__ bout,
                      float* __restrict__ OUT){
  const int g = blockIdx.x, tid = threadIdx.x;
  __shared__ float ah[4][520];
  for (int i = tid; i < 4 * 520; i += 256) {
    int bb = i / 520, k = i % 520;
    int b = g * 4 + bb;
    ah[bb][k] = (k < 512) ? ATTN[(size_t)b * 512 + k] : Ain[b * 8 + (k - 512)];
  }
  __syncthreads();
  #pragma unroll
  for (int part = 0; part < 2; ++part) {
    const int ho = part * 256 + tid;
    float a0 = bout[ho], a1 = a0, a2 = a0, a3 = a0;
    for (int k = 0; k < 520; ++k) {
      float w = WT[(size_t)k * 512 + ho];
      a0 += ah[0][k] * w; a1 += ah[1][k] * w; a2 += ah[2][k] * w; a3 += ah[3][k] * w;
    }
    OUT[(size_t)(g * 4 + 0) * 512 + ho] = a0;
    OUT[(size_t)(g * 4 + 1) * 512 + ho] = a1;
    OUT[(size_t)(g * 4 + 2) * 512 + ho] = a2;
    OUT[(size_t)(g * 4 + 3) * 512 + ho] = a3;
  }
}

// ---------------- host ----------------

extern "C" void kernel_launch(void* const* d_in, const int* in_sizes, int n_in,
                              void* d_out, int out_size, void* d_ws, size_t ws_size,
                              hipStream_t stream) {
  (void)in_sizes; (void)n_in; (void)out_size; (void)ws_size;
  const float* x    = (const float*)d_in[0];
  const float* a_in = (const float*)d_in[1];
  const float* tc   = (const float*)d_in[2];
  const float* mask = (const float*)d_in[3];
  const float* wdgx = (const float*)d_in[4];
  const float* bdgx = (const float*)d_in[5];
  const float* Wdgh = (const float*)d_in[6];
  const float* bdgh = (const float*)d_in[7];
  const float* Wm   = (const float*)d_in[8];
  const float* Um   = (const float*)d_in[9];
  const float* Vm   = (const float*)d_in[10];
  const float* bvv  = (const float*)d_in[11];
  const float* attv = (const float*)d_in[12];
  const float* Wout = (const float*)d_in[13];
  const float* bout = (const float*)d_in[14];

  char* ws = (char*)d_ws;
  size_t o = 0;
  auto al = [&](size_t sz) { size_t r = o; o += (sz + 255) & ~(size_t)255; return r; };
  u32*   flags = (u32*)  (ws + al(16 * 128 * 4));
  float* XMEAN = (float*)(ws + al(256));
  float* PX    = (float*)(ws + al((size_t)NS * 64 * 4));
  float* PM    = (float*)(ws + al((size_t)NS * 64 * 4));
  u16*   XHAT  = (u16*)  (ws + al((size_t)NS * NB * 64 * 2));
  u16*   MASKB = (u16*)  (ws + al((size_t)NS * NB * 64 * 2));
  u16*   DELTA = (u16*)  (ws + al((size_t)NS * NB * 64 * 2));
  u16*   HDECB = (u16*)  (ws + al((size_t)NB * NH * 2));
  u16*   RHB   = (u16*)  (ws + al((size_t)NB * NH * 2));
  u16*   XPART = (u16*)  (ws + al((size_t)2 * 16 * 16 * 1536 * 2));
  u16*   GAMB  = (u16*)  (ws + al((size_t)2 * 16 * 16 * 512 * 2));
  u16*   HALL  = (u16*)  (ws + al((size_t)NS * NB * NH * 2));
  float* ATTN  = (float*)(ws + al((size_t)NB * NH * 4));
  float* WT    = (float*)(ws + al((size_t)520 * 512 * 4));

  hipMemsetAsync(flags, 0, 16 * 128 * 4, stream);

  transpose_k<<<(520 * 512 + 255) / 256, 256, 0, stream>>>(Wout, WT);
  mean1_k<<<NS, 256, 0, stream>>>(x, mask, PX, PM);
  mean2_k<<<1, 64, 0, stream>>>(PX, PM, XMEAN);
  prep_k<<<NB * ND / 256, 256, 0, stream>>>(x, mask, tc, wdgx, bdgx, XMEAN, XHAT, MASKB, DELTA);
  grud_rnn<<<112, 256, 0, stream>>>(Um, Wm, Vm, bvv, Wdgh, bdgh, XHAT, MASKB, DELTA,
                                    HDECB, RHB, XPART, GAMB, HALL, flags);
  attn_k<<<NB, 256, 0, stream>>>(HALL, attv, ATTN);
  out_k<<<64, 256, 0, stream>>>(ATTN, a_in, WT, bout, (float*)d_out);
}